// Round 3
// baseline (195.583 us; speedup 1.0000x reference)
//
#include <hip/hip_runtime.h>
#include <hip/hip_bf16.h>

// y_i = x_i^T Q x_i + b^T x_i + c ; N=16384, D=1024, fp32.
// Round 7: kill xv global traffic. R5/R6 invariant: dur == FETCH/2.7TB/s
// (200MB->77us, 298MB->107us) -> fetch-bound. Biggest slice: x re-read
// for the fused dot, multiplied by the K-split factor. Fix: full-K blocks
// via INTRA-block K-split: 8 waves = 2 row-groups x 4 kq over 32 rows.
// Per round the 4 kq-partial C tiles are summed through LDS (8KB), and
// the dot's x values are extracted from the A-FRAGMENTS (kq-owner waves
// dump A regs -> 17KB xv LDS buffer per 256-col phase, dbuf, static reg
// indices) -> x read ONCE (64 MB). Q reg-staged bf16 (cvt once, store
// side), single 33KB tile, 2 barriers/round. Full-K -> direct y stores,
// no atomics/memset. LDS 76KB -> 2 blocks/CU; launch_bounds(512,4) caps
// 128 unified regs (est ~75 VGPR + 32 AGPR A-frags). Fetch target
// 100-140MB -> 35-48us if the 2.7TB/s rate holds.

#define DD 1024
#define TROW 2064        // Q-tile row stride bytes: 1024 bf16 + 8 pad
#define XROW 272         // xv row stride shorts: 256 + 16 pad (bank-free)

typedef short v8s __attribute__((ext_vector_type(8)));
typedef float v4f __attribute__((ext_vector_type(4)));

__device__ __forceinline__ short f2b(float f) {
    union { __hip_bfloat16 h; short s; } u;
    u.h = __float2bfloat16(f);
    return u.s;
}

__global__ __launch_bounds__(512, 4)
void quad_kernel(const float* __restrict__ x, const float* __restrict__ Q,
                 const float* __restrict__ bvec, const float* __restrict__ cptr,
                 float* __restrict__ y)
{
    __shared__ __align__(16) char  tile[16 * TROW];          // 33.0 KB
    __shared__ float parts[2][4][16][16];                    //  8.0 KB
    __shared__ __align__(16) short xvb[2][32][XROW];         // 34.0 KB

    const int tid  = threadIdx.x;
    const int lane = tid & 63;
    const int wave = tid >> 6;       // 0..7
    const int quad = lane >> 4;
    const int l15  = lane & 15;
    const int kq   = wave & 3;       // K quarter this wave owns
    const int rg   = wave >> 2;      // row group 0..1

    const int row_base = blockIdx.x * 32;

    // staging map: tile = 16 Qrows x 1024 floats = 4096 float4 / 512 thr
    const int sn = tid >> 8;         // 0..1 (+2i below)
    const int sk = tid & 255;        // float4 index within row

    // ---- prologue: issue tile-0 prefetch first (hides under A-load) ----
    float4 pf[8];
    #pragma unroll
    for (int i = 0; i < 8; ++i)
        pf[i] = *(const float4*)(Q + (size_t)(sn + 2 * i) * DD + sk * 4);

    // ---- A = x[32 rows][kq*256 ..+256) bf16 frags (32 AGPRs/wave) ----
    // A layout (16x16x32): m = lane&15, k = quad*8 + j
    v8s a[8];
    {
        const float* xr = x + (size_t)(row_base + rg * 16 + l15) * DD + kq * 256 + quad * 8;
        #pragma unroll
        for (int s = 0; s < 8; ++s) {
            const float4 f0 = *(const float4*)(xr + s * 32);
            const float4 f1 = *(const float4*)(xr + s * 32 + 4);
            v8s t;
            t[0]=f2b(f0.x); t[1]=f2b(f0.y); t[2]=f2b(f0.z); t[3]=f2b(f0.w);
            t[4]=f2b(f1.x); t[5]=f2b(f1.y); t[6]=f2b(f1.z); t[7]=f2b(f1.w);
            a[s] = t;
            asm volatile("" : "+a"(a[s]));   // steer to AGPR
        }
    }

    // dump xv for T=0: waves with kq==0 write their A regs (cols 0..255)
    if (kq == 0) {
        char* d = (char*)&xvb[0][rg * 16 + l15][0] + quad * 16;
        #pragma unroll
        for (int s = 0; s < 8; ++s) *(v8s*)(d + s * 64) = a[s];
    }

    // store tile 0 (fp32->bf16), issue pf(1)
    #pragma unroll
    for (int i = 0; i < 8; ++i) {
        const float4 f = pf[i];
        short4 s4; s4.x=f2b(f.x); s4.y=f2b(f.y); s4.z=f2b(f.z); s4.w=f2b(f.w);
        *(short4*)(tile + (sn + 2 * i) * TROW + sk * 8) = s4;
    }
    #pragma unroll
    for (int i = 0; i < 8; ++i)
        pf[i] = *(const float4*)(Q + (size_t)(16 + sn + 2 * i) * DD + sk * 4);

    __syncthreads();

    // ---- loop-invariant pointers ----
    const char* bp = tile + l15 * TROW + kq * 512 + quad * 16;   // B-frag base
    float* pw = &parts[rg][kq][quad * 4][0] + l15;               // partial write
    const int m = tid >> 4;          // 0..31: x-row this thread reduces
    const int c = tid & 15;          // col-in-tile
    const float* pr = &parts[m >> 4][0][m & 15][c];              // partial read

    float acc = 0.f;

    for (int t = 0; t < 64; ++t) {
        const float bb = bvec[t * 16 + c];      // early issue, used in (e)

        // (a) MFMA: 8 k-steps over this wave's K-quarter
        v4f cf = (v4f){0.f, 0.f, 0.f, 0.f};
        #pragma unroll
        for (int s = 0; s < 8; ++s) {
            const v8s bf = *(const v8s*)(bp + s * 64);
            cf = __builtin_amdgcn_mfma_f32_16x16x32_bf16(a[s], bf, cf, 0, 0, 0);
        }
        // (b) partial C -> LDS  (C: row = quad*4+r, col = l15)
        #pragma unroll
        for (int r = 0; r < 4; ++r) pw[r * 16] = cf[r];

        __syncthreads();   // alpha: tile-t reads done, partials written

        // (d) store next tile, prefetch t+2, phase-boundary xv dump
        if (t < 63) {
            #pragma unroll
            for (int i = 0; i < 8; ++i) {
                const float4 f = pf[i];
                short4 s4; s4.x=f2b(f.x); s4.y=f2b(f.y); s4.z=f2b(f.z); s4.w=f2b(f.w);
                *(short4*)(tile + (sn + 2 * i) * TROW + sk * 8) = s4;
            }
            if (t < 62) {
                #pragma unroll
                for (int i = 0; i < 8; ++i)
                    pf[i] = *(const float4*)(Q + (size_t)((t + 2) * 16 + sn + 2 * i) * DD + sk * 4);
            }
        }
        if ((t & 15) == 15 && t < 48 && kq == (t >> 4) + 1) {
            // dump xv for next 256-col phase into the other buffer
            char* d = (char*)&xvb[((t >> 4) + 1) & 1][rg * 16 + l15][0] + quad * 16;
            #pragma unroll
            for (int s = 0; s < 8; ++s) *(v8s*)(d + s * 64) = a[s];
        }

        // (e) sum 4 kq-partials, dot with x from LDS
        const float cs = pr[0] + pr[256] + pr[512] + pr[768];
        const int xo = ((t >> 4) & 1) * (32 * XROW) + m * XROW + (t & 15) * 16 + c;
        union { unsigned u; float f; } uu;
        uu.u = ((unsigned)(unsigned short)((const short*)xvb)[xo]) << 16;
        acc += (cs + bb) * uu.f;

        __syncthreads();   // beta: partials free, tile t+1 ready
    }

    // ---- reduce the 16 col-threads of each row, direct store ----
    float v = acc;
    v += __shfl_xor(v, 1); v += __shfl_xor(v, 2);
    v += __shfl_xor(v, 4); v += __shfl_xor(v, 8);
    if (c == 0) y[row_base + m] = v + cptr[0];
}

extern "C" void kernel_launch(void* const* d_in, const int* in_sizes, int n_in,
                              void* d_out, int out_size, void* d_ws, size_t ws_size,
                              hipStream_t stream)
{
    const float* x = (const float*)d_in[0];
    const float* Q = (const float*)d_in[1];
    const float* b = (const float*)d_in[2];
    const float* c = (const float*)d_in[3];
    float* y = (float*)d_out;

    // full-K blocks own their rows exclusively: direct stores, no memset
    quad_kernel<<<dim3(512), dim3(512), 0, stream>>>(x, Q, b, c, y);
}

// Round 4
// 167.575 us; speedup vs baseline: 1.1671x; 1.1671x over previous
//
#include <hip/hip_runtime.h>
#include <hip/hip_bf16.h>

// y_i = x_i^T Q x_i + b^T x_i + c ; N=16384, D=1024, fp32.
// Round 8: M=64 + distributed dot. R7 post-mortem: fetch fixed (49MB) but
// Q-delivery bound: 512 blocks x 4MB = 2GB logical Q from L3 at ~15.7TB/s
// = 127us (Q evicted from L2: 4MB Q == L2 size, x streams through).
// Q logical traffic = (16384/M)*4MB -> M=32 floor ~60us. Fixes:
//  - dot distributes over kq-partials: each wave dots its OWN cf partial
//    with xv -> NO parts LDS, NO 2nd barrier (dbuf tile, 1 barrier/round)
//  - freed LDS -> M=64: tile dbuf 64KB + xv dbuf 66KB + yred 1KB = 131KB,
//    grid 256 = 1 block/CU, Q logical 1GB (L2 floor 29us); all blocks
//    launch together w/ identical schedules -> small per-XCD Q window
//  - tile XOR-swizzle (byte ^ ((col&7)<<4)): R7's linear 2048B stride was
//    16-way conflict on B-frag ds_read_b128 (10.7M conflict-cycles)
//  - Q read "transposed" (tile rows = Q rows, coalesced): valid since
//    x^T Q x == x^T Q^T x.
// A = a[2][8] = 64 AGPR + ~85 VGPR ~ 149 unified <= 256 @ (512,2).
// Full-K blocks -> direct y stores, no atomics/memset.

#define DD 1024
#define TROWB 2048       // tile row bytes (1024 k * 2B bf16), linear layout
#define XROW 264         // xv row stride in shorts (256 + 8); 528B, 16B-aligned

typedef short v8s __attribute__((ext_vector_type(8)));
typedef float v4f __attribute__((ext_vector_type(4)));

__device__ __forceinline__ short f2b(float f) {
    union { __hip_bfloat16 h; short s; } u;
    u.h = __float2bfloat16(f);
    return u.s;
}
__device__ __forceinline__ float b2f(short s) {
    union { unsigned u; float f; } uu;
    uu.u = ((unsigned)(unsigned short)s) << 16;
    return uu.f;
}

__global__ __launch_bounds__(512, 2)
void quad_kernel(const float* __restrict__ x, const float* __restrict__ Q,
                 const float* __restrict__ bvec, const float* __restrict__ cptr,
                 float* __restrict__ y)
{
    __shared__ __align__(16) char  tile[2][16 * TROWB];   // 64 KB, dbuf
    __shared__ __align__(16) short xvb[2][64 * XROW];     // 66 KB, dbuf per 256-col phase
    __shared__ float yred[4][64];                         //  1 KB

    const int tid  = threadIdx.x;
    const int lane = tid & 63;
    const int wave = tid >> 6;       // 0..7
    const int quad = lane >> 4;
    const int l15  = lane & 15;
    const int kq   = wave & 3;       // K quarter this wave owns
    const int rg   = wave >> 2;      // row group 0..1 (32 rows each)

    const int row_base = blockIdx.x * 64;

    // ---- prologue: issue pf(tile 0) first (hides under A-load) ----
    // staging map: idx = tid + i*512; row = idx>>8 (0..15 = Q-row in tile),
    // slot = idx&255 (8B/4-float unit); LDS byte = slot*8 ^ ((row&7)<<4)
    float4 pf[8];
    #pragma unroll
    for (int i = 0; i < 8; ++i) {
        const int idx = tid + i * 512;
        pf[i] = *(const float4*)(Q + (size_t)(idx >> 8) * DD + (idx & 255) * 4);
    }

    // ---- A = x[64 rows][kq*256 ..+256) bf16 frags (64 AGPRs/wave) ----
    // A layout (16x16x32): m = lane&15, k = quad*8 + j
    v8s a[2][8];
    #pragma unroll
    for (int g = 0; g < 2; ++g) {
        const float* xr = x + (size_t)(row_base + rg * 32 + g * 16 + l15) * DD + kq * 256 + quad * 8;
        #pragma unroll
        for (int s = 0; s < 8; ++s) {
            const float4 f0 = *(const float4*)(xr + s * 32);
            const float4 f1 = *(const float4*)(xr + s * 32 + 4);
            v8s t;
            t[0]=f2b(f0.x); t[1]=f2b(f0.y); t[2]=f2b(f0.z); t[3]=f2b(f0.w);
            t[4]=f2b(f1.x); t[5]=f2b(f1.y); t[6]=f2b(f1.z); t[7]=f2b(f1.w);
            a[g][s] = t;
            asm volatile("" : "+a"(a[g][s]));   // steer to AGPR
        }
    }

    // dump xv phase 0 (cols 0..255): kq==0 waves write their A frags
    if (kq == 0) {
        #pragma unroll
        for (int g = 0; g < 2; ++g) {
            char* d = (char*)&xvb[0][(size_t)(rg * 32 + g * 16 + l15) * XROW];
            #pragma unroll
            for (int s = 0; s < 8; ++s)
                *(v8s*)(d + s * 64 + quad * 16) = a[g][s];
        }
    }

    // store tile 0 (fp32->bf16, swizzled), issue pf(tile 1)
    #pragma unroll
    for (int i = 0; i < 8; ++i) {
        const int idx = tid + i * 512;
        const int row = idx >> 8, slot = idx & 255;
        const float4 f = pf[i];
        short4 s4; s4.x=f2b(f.x); s4.y=f2b(f.y); s4.z=f2b(f.z); s4.w=f2b(f.w);
        *(short4*)(&tile[0][row * TROWB + ((slot * 8) ^ ((row & 7) << 4))]) = s4;
    }
    #pragma unroll
    for (int i = 0; i < 8; ++i) {
        const int idx = tid + i * 512;
        pf[i] = *(const float4*)(Q + (size_t)(16 + (idx >> 8)) * DD + (idx & 255) * 4);
    }
    __syncthreads();

    const int xorc = (l15 & 7) << 4;
    float acc[2][4];
    #pragma unroll
    for (int g = 0; g < 2; ++g)
        #pragma unroll
        for (int r = 0; r < 4; ++r) acc[g][r] = 0.f;

    for (int t = 0; t < 64; ++t) {
        // (a) stage tile t+1 into buf (t+1)&1 (other buffer: no conflict
        //     with this round's readers), then issue pf(t+2)
        if (t < 63) {
            char* db = &tile[(t + 1) & 1][0];
            #pragma unroll
            for (int i = 0; i < 8; ++i) {
                const int idx = tid + i * 512;
                const int row = idx >> 8, slot = idx & 255;
                const float4 f = pf[i];
                short4 s4; s4.x=f2b(f.x); s4.y=f2b(f.y); s4.z=f2b(f.z); s4.w=f2b(f.w);
                *(short4*)(db + row * TROWB + ((slot * 8) ^ ((row & 7) << 4))) = s4;
            }
            if (t < 62) {
                #pragma unroll
                for (int i = 0; i < 8; ++i) {
                    const int idx = tid + i * 512;
                    pf[i] = *(const float4*)(Q + (size_t)((t + 2) * 16 + (idx >> 8)) * DD + (idx & 255) * 4);
                }
            }
        }

        // (b) xv dump for next 256-col phase at phase start (15 rounds slack;
        //     target buffer was last read in the round before previous barrier)
        if ((t & 15) == 0 && t < 48 && kq == (t >> 4) + 1) {
            const int nb = ((t >> 4) + 1) & 1;
            #pragma unroll
            for (int g = 0; g < 2; ++g) {
                char* d = (char*)&xvb[nb][(size_t)(rg * 32 + g * 16 + l15) * XROW];
                #pragma unroll
                for (int s = 0; s < 8; ++s)
                    *(v8s*)(d + s * 64 + quad * 16) = a[g][s];
            }
        }

        // bias: added by kq==0 waves only (once per column across kq)
        const float bb = (kq == 0) ? bvec[t * 16 + l15] : 0.f;

        // (c) MFMA on tile[t&1]: wave's kq-slice, 2 independent chains
        const char* tb = &tile[t & 1][0] + l15 * TROWB;
        v4f cf[2];
        cf[0] = (v4f){0.f, 0.f, 0.f, 0.f};
        cf[1] = (v4f){0.f, 0.f, 0.f, 0.f};
        #pragma unroll
        for (int s = 0; s < 8; ++s) {
            const v8s bf = *(const v8s*)(tb + ((kq * 512 + s * 64 + quad * 16) ^ xorc));
            cf[0] = __builtin_amdgcn_mfma_f32_16x16x32_bf16(a[0][s], bf, cf[0], 0, 0, 0);
            cf[1] = __builtin_amdgcn_mfma_f32_16x16x32_bf16(a[1][s], bf, cf[1], 0, 0, 0);
        }

        // (d) distributed dot: each wave dots its OWN kq-partial with xv.
        // C layout: row = quad*4 + r, col = l15.
        const short* xp = &xvb[(t >> 4) & 1][0] + (t & 15) * 16 + l15;
        #pragma unroll
        for (int g = 0; g < 2; ++g)
            #pragma unroll
            for (int r = 0; r < 4; ++r) {
                const int row = rg * 32 + g * 16 + quad * 4 + r;
                acc[g][r] += (cf[g][r] + bb) * b2f(xp[(size_t)row * XROW]);
            }

        __syncthreads();   // tile t reads done; tile t+1 written; xv dump visible
    }

    // ---- reduce: 16 l15-lanes (shfl) then 4 kq-waves (LDS), direct store ----
    #pragma unroll
    for (int g = 0; g < 2; ++g)
        #pragma unroll
        for (int r = 0; r < 4; ++r) {
            float v = acc[g][r];
            v += __shfl_xor(v, 1); v += __shfl_xor(v, 2);
            v += __shfl_xor(v, 4); v += __shfl_xor(v, 8);
            if (l15 == 0)
                yred[kq][rg * 32 + g * 16 + quad * 4 + r] = v;
        }
    __syncthreads();
    if (tid < 64)
        y[row_base + tid] = yred[0][tid] + yred[1][tid] + yred[2][tid] + yred[3][tid] + cptr[0];
}

extern "C" void kernel_launch(void* const* d_in, const int* in_sizes, int n_in,
                              void* d_out, int out_size, void* d_ws, size_t ws_size,
                              hipStream_t stream)
{
    const float* x = (const float*)d_in[0];
    const float* Q = (const float*)d_in[1];
    const float* b = (const float*)d_in[2];
    const float* c = (const float*)d_in[3];
    float* y = (float*)d_out;

    // full-K blocks own their rows exclusively: direct stores, no memset
    quad_kernel<<<dim3(256), dim3(512), 0, stream>>>(x, Q, b, c, y);
}